// Round 4
// baseline (402.291 us; speedup 1.0000x reference)
//
#include <hip/hip_runtime.h>
#include <hip/hip_bf16.h>

// CausalSelfAttention on gfx950: bf16 MFMA pipeline, flash v4.
// x(4,2048,1024)f32, Wqkv(1024,3072)f32, Wproj(1024,1024)f32
// out = [ y (8192*1024) | k (4,16,2048,64) | v (4,16,2048,64) ] fp32
//
// Flash v4: 32x32x16 MFMA; P stays in registers (C-layout col=lane&31=q is
// already the PV B-operand q-layout; s-halves exchanged via shfl_xor 32).
// Single-barrier double-buffered K/V prefetch loop (staging latency hidden
// behind compute). Block = q-tile pairs {2m,2m+1,30-2m,31-2m} (balanced).

typedef __bf16 bf16;
typedef __attribute__((ext_vector_type(8))) __bf16 bf16x8;
typedef __attribute__((ext_vector_type(4))) __bf16 bf16x4;
typedef __attribute__((ext_vector_type(4))) float f32x4;
typedef __attribute__((ext_vector_type(16))) float f32x16;

#define AS_G __attribute__((address_space(1)))
#define AS_L __attribute__((address_space(3)))

// q pre-scale: 1/sqrt(64) * log2(e)  (softmax in base-2; folded into WqkvT)
#define QSCALE 0.1803368801111204f

__device__ __forceinline__ void gld_lds16(const bf16* g, bf16* l) {
  __builtin_amdgcn_global_load_lds((const AS_G void*)g, (AS_L void*)l, 16, 0, 0);
}

// ------------- prep: cast x->bf16 ; transpose+cast both W (QSCALE folded) -------------
__global__ __launch_bounds__(256) void k_prep(const float* __restrict__ x,
                                              const float* __restrict__ Wqkv,
                                              const float* __restrict__ Wproj,
                                              bf16* __restrict__ xb,
                                              bf16* __restrict__ wqkvT,
                                              bf16* __restrict__ wprojT) {
  const int bid = blockIdx.x, tid = threadIdx.x;
  if (bid < 4096) {  // cast x
    int i = (bid * 256 + tid) * 8;
    float4 a = *(const float4*)(x + i);
    float4 b = *(const float4*)(x + i + 4);
    bf16x8 o;
    o[0] = (bf16)a.x; o[1] = (bf16)a.y; o[2] = (bf16)a.z; o[3] = (bf16)a.w;
    o[4] = (bf16)b.x; o[5] = (bf16)b.y; o[6] = (bf16)b.z; o[7] = (bf16)b.w;
    *(bf16x8*)(xb + i) = o;
    return;
  }
  __shared__ float tile[32][33];
  const float* in; bf16* outp; int N, bx, by; bool isqkv;
  if (bid < 7168) { int t = bid - 4096; in = Wqkv; outp = wqkvT; N = 3072; bx = (t % 96) * 32; by = (t / 96) * 32; isqkv = true; }
  else            { int t = bid - 7168; in = Wproj; outp = wprojT; N = 1024; bx = (t % 32) * 32; by = (t / 32) * 32; isqkv = false; }
  const int tx = tid & 31, ty = tid >> 5;  // 32 x 8
#pragma unroll
  for (int i = 0; i < 4; ++i)
    tile[ty + i * 8][tx] = in[(size_t)(by + ty + i * 8) * N + bx + tx];
  __syncthreads();
#pragma unroll
  for (int i = 0; i < 4; ++i) {
    int n = bx + ty + i * 8;
    float s = (isqkv && n < 1024) ? QSCALE : 1.0f;
    outp[(size_t)n * 1024 + by + tx] = (bf16)(tile[tx][ty + i * 8] * s);
  }
}

// ---------------- m97-style 128x128 bf16 GEMM mainloop ----------------
__device__ __forceinline__ void gemm_tile_128(const bf16* __restrict__ A,
                                              const bf16* __restrict__ Bt,
                                              int m0, int n0,
                                              bf16* As, bf16* Bs,
                                              f32x4 acc[4][4]) {
  const int tid = threadIdx.x;
  const int w = tid >> 6, lane = tid & 63, lo = lane & 15, hi = lane >> 4;
  const int wm = w >> 1, wn = w & 1;
#pragma unroll 1
  for (int k0 = 0; k0 < 1024; k0 += 32) {
#pragma unroll
    for (int p = 0; p < 2; ++p) {
      int u = tid + 256 * p;
      int row = u >> 2, cs = u & 3;
      int g = cs ^ ((row >> 1) & 3);
      gld_lds16(A + (size_t)(m0 + row) * 1024 + k0 + g * 8, As + p * 2048 + w * 512);
      gld_lds16(Bt + (size_t)(n0 + row) * 1024 + k0 + g * 8, Bs + p * 2048 + w * 512);
    }
    __syncthreads();
    bf16x8 af[4], bfr[4];
#pragma unroll
    for (int i = 0; i < 4; ++i) {
      int row = wm * 64 + i * 16 + lo;
      af[i] = *(const bf16x8*)(As + row * 32 + (hi ^ ((row >> 1) & 3)) * 8);
    }
#pragma unroll
    for (int j = 0; j < 4; ++j) {
      int row = wn * 64 + j * 16 + lo;
      bfr[j] = *(const bf16x8*)(Bs + row * 32 + (hi ^ ((row >> 1) & 3)) * 8);
    }
#pragma unroll
    for (int i = 0; i < 4; ++i)
#pragma unroll
      for (int j = 0; j < 4; ++j)
        acc[i][j] = __builtin_amdgcn_mfma_f32_16x16x32_bf16(af[i], bfr[j], acc[i][j], 0, 0, 0);
    __syncthreads();
  }
}

// -------- GEMM1: qkv = x @ Wqkv; epilogue scatters q/k bf16, k/v fp32, V^T bf16 --------
__global__ __launch_bounds__(256) void k_gemm_qkv(const bf16* __restrict__ x,
                                                  const bf16* __restrict__ WqkvT,
                                                  bf16* __restrict__ qb, bf16* __restrict__ kb,
                                                  bf16* __restrict__ vtb,
                                                  float* __restrict__ outk, float* __restrict__ outv) {
  __shared__ bf16 As[128 * 32], Bs[128 * 32];
  f32x4 acc[4][4] = {};
  int m0 = blockIdx.y * 128, n0 = blockIdx.x * 128;
  gemm_tile_128(x, WqkvT, m0, n0, As, Bs, acc);
  const int tid = threadIdx.x;
  const int w = tid >> 6, lane = tid & 63, lo = lane & 15, hi = lane >> 4;
  const int wm = w >> 1, wn = w & 1;
#pragma unroll
  for (int i = 0; i < 4; ++i) {
    int growbase = m0 + wm * 64 + i * 16 + hi * 4;   // b*2048 + t0, 4 consecutive t
    int b = growbase >> 11, t0 = growbase & 2047;
#pragma unroll
    for (int j = 0; j < 4; ++j) {
      int gcol = n0 + wn * 64 + j * 16 + lo;         // 0..3071
      int part = gcol >> 10;                         // 0=q 1=k 2=v (uniform per block)
      int cc = gcol & 1023, h = cc >> 6, d = cc & 63;
      size_t idx0 = ((size_t)(b * 16 + h) * 2048 + t0) * 64 + d;
      if (part == 0) {
#pragma unroll
        for (int r = 0; r < 4; ++r) qb[idx0 + (size_t)r * 64] = (bf16)acc[i][j][r];
      } else if (part == 1) {
#pragma unroll
        for (int r = 0; r < 4; ++r) {
          float val = acc[i][j][r];
          kb[idx0 + (size_t)r * 64] = (bf16)val;
          outk[idx0 + (size_t)r * 64] = val;
        }
      } else {
        bf16x4 pk;
#pragma unroll
        for (int r = 0; r < 4; ++r) {
          float val = acc[i][j][r];
          outv[idx0 + (size_t)r * 64] = val;
          pk[r] = (bf16)val;
        }
        *(bf16x4*)(vtb + ((size_t)(b * 16 + h) * 64 + d) * 2048 + t0) = pk;
      }
    }
  }
}

// ---------------- GEMM2: out_y = y_att @ Wproj ----------------
__global__ __launch_bounds__(256) void k_gemm_proj(const bf16* __restrict__ yb,
                                                   const bf16* __restrict__ WprojT,
                                                   float* __restrict__ out) {
  __shared__ bf16 As[128 * 32], Bs[128 * 32];
  f32x4 acc[4][4] = {};
  int m0 = blockIdx.y * 128, n0 = blockIdx.x * 128;
  gemm_tile_128(yb, WprojT, m0, n0, As, Bs, acc);
  const int tid = threadIdx.x;
  const int w = tid >> 6, lane = tid & 63, lo = lane & 15, hi = lane >> 4;
  const int wm = w >> 1, wn = w & 1;
#pragma unroll
  for (int i = 0; i < 4; ++i)
#pragma unroll
    for (int j = 0; j < 4; ++j)
#pragma unroll
      for (int r = 0; r < 4; ++r) {
        int grow = m0 + wm * 64 + i * 16 + hi * 4 + r;
        int gcol = n0 + wn * 64 + j * 16 + lo;
        out[(size_t)grow * 1024 + gcol] = acc[i][j][r];
      }
}

// ---------------- flash v4 helpers ----------------
__device__ __forceinline__ void stage_kv(const bf16* kp, const bf16* vtp,
                                         bf16* KsD, bf16* VsD, int st, int tid, int w) {
  const int s0 = st * 64;
#pragma unroll
  for (int pp = 0; pp < 2; ++pp) {
    int u = tid + 256 * pp;
    int row = u >> 3, c = u & 7, g = c ^ (row & 7);
    gld_lds16(kp + (size_t)(s0 + row) * 64 + g * 8, KsD + pp * 2048 + w * 512);
    gld_lds16(vtp + (size_t)row * 2048 + s0 + g * 8, VsD + pp * 2048 + w * 512);
  }
}

// exp2 + causal mask + bf16 pack into quads (C rows 8g+4hi+c) + hi-half exchange
__device__ __forceinline__ void soft_pack(const f32x16& sa, bool mk, int sbase, int qg,
                                          int hi, float& l, uint2 uo[4], uint2 ux[4]) {
#pragma unroll
  for (int g = 0; g < 4; ++g) {
    bf16x4 pk;
#pragma unroll
    for (int c = 0; c < 4; ++c) {
      float ev = exp2f(sa[4 * g + c]);
      if (mk) { int sg = sbase + c + 8 * g + 4 * hi; if (sg > qg) ev = 0.f; }
      bf16 pb = (bf16)ev;
      pk[c] = pb;
      l += (float)pb;   // l consistent with bf16-rounded P used in PV
    }
    uint2 uu; __builtin_memcpy(&uu, &pk, 8);
    uo[g] = uu;
    ux[g].x = __shfl_xor(uu.x, 32, 64);
    ux[g].y = __shfl_xor(uu.y, 32, 64);
  }
}

// PV B-operand: hi=0 lanes need rows [16t..16t+7] = [own quad 2t | partner quad 2t];
// hi=1 lanes need rows [16t+8..16t+15] = [partner quad 2t+1 | own quad 2t+1]
__device__ __forceinline__ bf16x8 asm_b(int hi, uint2 own, uint2 rcv) {
  unsigned int r[4];
  if (hi == 0) { r[0] = own.x; r[1] = own.y; r[2] = rcv.x; r[3] = rcv.y; }
  else         { r[0] = rcv.x; r[1] = rcv.y; r[2] = own.x; r[3] = own.y; }
  bf16x8 b; __builtin_memcpy(&b, r, 16); return b;
}

__device__ __forceinline__ void wr_o(bf16* __restrict__ y, size_t base, int dbase, int hi,
                                     const f32x16& O, float inv) {
#pragma unroll
  for (int g = 0; g < 4; ++g) {
    bf16x4 yk;
#pragma unroll
    for (int c = 0; c < 4; ++c) yk[c] = (bf16)(O[4 * g + c] * inv);
    *(bf16x4*)(y + base + dbase + 8 * g + 4 * hi) = yk;
  }
}

// ---------------- flash v4 ----------------
// grid 512: block = (bh, m); q-tiles {2m,2m+1} (Qt1, skippable) + {30-2m,31-2m} (Qt0).
// S^T = K Q^T per 32x32 tile: C col=lane&31=q, rows=s pattern. P kept in regs.
__global__ __launch_bounds__(256, 2) void k_flash(const bf16* __restrict__ q,
                                                  const bf16* __restrict__ k,
                                                  const bf16* __restrict__ vt,
                                                  bf16* __restrict__ y) {
  __shared__ bf16 Ks[2][64 * 64];   // [s][d], chunk-swizzled by row&7
  __shared__ bf16 Vs[2][64 * 64];   // [d][s], chunk-swizzled by row&7
  const int bi = blockIdx.x;
  const int bh = (bi & 7) + 8 * (bi >> 6);   // XCD-sliced: all 8 m-blocks of bh share bi&7
  const int m = (bi >> 3) & 7;
  const int j1 = 2 * m, j2 = 2 * m + 1, jB2 = 30 - 2 * m, jB1 = 31 - 2 * m;
  const int tid = threadIdx.x, w = tid >> 6, lane = tid & 63;
  const int col = lane & 31, hi = lane >> 5, sub = col & 15, half = col >> 4;
  const bf16* qp = q + (size_t)bh * 2048 * 64;
  const bf16* kp = k + (size_t)bh * 2048 * 64;
  const bf16* vtp = vt + (size_t)bh * 64 * 2048;

  const int qg0 = (half ? jB1 : jB2) * 64 + w * 16 + sub;   // Qt0: B-pair (always active)
  const int qg1 = (half ? j2 : j1) * 64 + w * 16 + sub;     // Qt1: A-pair (skippable)

  // Q fragments (B-operand: n=q=lane&31, k=d=(lane>>5)*8+kc*16+j) — loop-invariant
  bf16x8 qf0[4], qf1[4];
#pragma unroll
  for (int kc = 0; kc < 4; ++kc) {
    qf0[kc] = *(const bf16x8*)(qp + (size_t)qg0 * 64 + kc * 16 + hi * 8);
    qf1[kc] = *(const bf16x8*)(qp + (size_t)qg1 * 64 + kc * 16 + hi * 8);
  }

  f32x16 O00 = {}, O10 = {}, O01 = {}, O11 = {};  // O[Dt][Qt], O^T: row=d, col=q
  float l0 = 0.f, l1 = 0.f;

  stage_kv(kp, vtp, Ks[0], Vs[0], 0, tid, w);

  for (int st = 0; st <= jB1; ++st) {
    const int p = st & 1;
    const int s0 = st * 64;
    __syncthreads();                               // drains prefetch of buf p; all reads of p^1 done
    if (st < jB1) stage_kv(kp, vtp, Ks[p ^ 1], Vs[p ^ 1], st + 1, tid, w);  // overlaps compute
    const bool act1 = (st <= j2);
    const bf16* KsP = Ks[p];
    const bf16* VsP = Vs[p];
#pragma unroll
    for (int St = 0; St < 2; ++St) {
      const int sbase = s0 + St * 32;
      // --- S^T tiles: A = K (m=s), B = Q ---
      f32x16 sa0 = {}, sa1 = {};
#pragma unroll
      for (int kc = 0; kc < 4; ++kc) {
        int srow = St * 32 + col;
        int cc = kc * 2 + hi;
        bf16x8 kfr = *(const bf16x8*)(KsP + srow * 64 + ((cc ^ (srow & 7)) * 8));
        sa0 = __builtin_amdgcn_mfma_f32_32x32x16_bf16(kfr, qf0[kc], sa0, 0, 0, 0);
        if (act1) sa1 = __builtin_amdgcn_mfma_f32_32x32x16_bf16(kfr, qf1[kc], sa1, 0, 0, 0);
      }
      const bool mk0 = (sbase + 31) > (jB2 * 64 + w * 16);
      const bool mk1 = (sbase + 31) > (j1 * 64 + w * 16);
      uint2 u0[4], x0[4], u1[4], x1[4];
      soft_pack(sa0, mk0, sbase, qg0, hi, l0, u0, x0);
      if (act1) soft_pack(sa1, mk1, sbase, qg1, hi, l1, u1, x1);
      // --- O^T += V^T P : A = V^T (m=d), B = P from regs ---
#pragma unroll
      for (int t = 0; t < 2; ++t) {
        bf16x8 b0 = asm_b(hi, u0[2 * t + hi], x0[2 * t + hi]);
        bf16x8 b1 = b0;
        if (act1) b1 = asm_b(hi, u1[2 * t + hi], x1[2 * t + hi]);
        int cc2 = (St * 2 + t) * 2 + hi;
#pragma unroll
        for (int Dt = 0; Dt < 2; ++Dt) {
          int vrow = Dt * 32 + col;
          bf16x8 vfr = *(const bf16x8*)(VsP + vrow * 64 + ((cc2 ^ (vrow & 7)) * 8));
          if (Dt == 0) {
            O00 = __builtin_amdgcn_mfma_f32_32x32x16_bf16(vfr, b0, O00, 0, 0, 0);
            if (act1) O01 = __builtin_amdgcn_mfma_f32_32x32x16_bf16(vfr, b1, O01, 0, 0, 0);
          } else {
            O10 = __builtin_amdgcn_mfma_f32_32x32x16_bf16(vfr, b0, O10, 0, 0, 0);
            if (act1) O11 = __builtin_amdgcn_mfma_f32_32x32x16_bf16(vfr, b1, O11, 0, 0, 0);
          }
        }
      }
    }
  }

  // l totals: own rows + partner (lane^32) rows
  const float lt0 = l0 + __shfl_xor(l0, 32, 64);
  const float lt1 = l1 + __shfl_xor(l1, 32, 64);
  const float inv0 = 1.0f / lt0, inv1 = 1.0f / lt1;
  const int b = bh >> 4, h = bh & 15;
  {
    size_t base = ((size_t)b * 2048 + qg0) * 1024 + h * 64;
    wr_o(y, base, 0, hi, O00, inv0);
    wr_o(y, base, 32, hi, O10, inv0);
  }
  {
    size_t base = ((size_t)b * 2048 + qg1) * 1024 + h * 64;
    wr_o(y, base, 0, hi, O01, inv1);
    wr_o(y, base, 32, hi, O11, inv1);
  }
}

// ---------------------------------------------------------------------------
extern "C" void kernel_launch(void* const* d_in, const int* in_sizes, int n_in,
                              void* d_out, int out_size, void* d_ws, size_t ws_size,
                              hipStream_t stream) {
  const float* x = (const float*)d_in[0];
  const float* Wqkv = (const float*)d_in[1];
  const float* Wproj = (const float*)d_in[2];
  float* out = (float*)d_out;

  const size_t YSZ = (size_t)8192 * 1024;
  char* ws = (char*)d_ws;
  bf16* xb = (bf16*)ws;      ws += (size_t)8192 * 1024 * 2;
  bf16* wqkvT = (bf16*)ws;   ws += (size_t)3072 * 1024 * 2;
  bf16* wprojT = (bf16*)ws;  ws += (size_t)1024 * 1024 * 2;
  bf16* qb = (bf16*)ws;      ws += (size_t)64 * 2048 * 64 * 2;
  bf16* kb = (bf16*)ws;      ws += (size_t)64 * 2048 * 64 * 2;
  bf16* vtb = (bf16*)ws;     ws += (size_t)64 * 2048 * 64 * 2;
  bf16* yb = (bf16*)ws;      // 88 MB total

  float* outy = out;
  float* outk = out + YSZ;
  float* outv = out + 2 * YSZ;

  k_prep<<<8192, 256, 0, stream>>>(x, Wqkv, Wproj, xb, wqkvT, wprojT);
  k_gemm_qkv<<<dim3(24, 64), 256, 0, stream>>>(xb, wqkvT, qb, kb, vtb, outk, outv);
  k_flash<<<512, 256, 0, stream>>>(qb, kb, vtb, yb);
  k_gemm_proj<<<dim3(8, 64), 256, 0, stream>>>(yb, wprojT, outy);
}